// Round 10
// baseline (151.364 us; speedup 1.0000x reference)
//
#include <hip/hip_runtime.h>
#include <hip/hip_bf16.h>

typedef __bf16 bf16;
typedef __bf16 bf16x4 __attribute__((ext_vector_type(4)));
typedef __bf16 bf16x8 __attribute__((ext_vector_type(8)));
typedef float  floatx4 __attribute__((ext_vector_type(4)));

#define D_MODEL   1024
#define NUM_HEADS 16
#define NUM_GROUPS 4
#define DK        64
#define SEQ_T     2048
#define BATCH     2
#define M_ROWS    (BATCH*SEQ_T)   // 4096
#define WINDOW    512
#define KV_DIM    (NUM_GROUPS*DK) // 256
#define N_QKV     (D_MODEL + 2*KV_DIM)  // 1536
// Q pre-scale: 1/sqrt(64) * log2(e)  (exp -> exp2 domain)
#define QSCALE    0.1803368801111204f
// log2(10000)/32
#define FREQ_C    0.4152410118609203f

#define GLDS16(g, l)                                                          \
    __builtin_amdgcn_global_load_lds(                                         \
        (const __attribute__((address_space(1))) void*)(g),                   \
        (__attribute__((address_space(3))) void*)(l), 16, 0, 0)

// ---------------------------------------------------------------------------
// Fused convert: 5 fp32 segments (x, WQ, WK, WV, WO) -> bf16 dsts.
// ---------------------------------------------------------------------------
__global__ __launch_bounds__(256)
void convert_all(const float* s0, bf16* d0, int c0,
                 const float* s1, bf16* d1, int c1,
                 const float* s2, bf16* d2, int c2,
                 const float* s3, bf16* d3, int c3,
                 const float* s4, bf16* d4, int c4)
{
    int id = blockIdx.x * 256 + threadIdx.x;
    const float* src; bf16* dst;
    if      (id < c0)         { src = s0; dst = d0; }
    else if ((id -= c0) < c1) { src = s1; dst = d1; }
    else if ((id -= c1) < c2) { src = s2; dst = d2; }
    else if ((id -= c2) < c3) { src = s3; dst = d3; }
    else if ((id -= c3) < c4) { src = s4; dst = d4; }
    else return;
    int i = id * 8;
    const float* s = src + i;
    float4 a = *(const float4*)s;
    float4 b = *(const float4*)(s + 4);
    bf16x8 v;
    v[0] = (bf16)a.x; v[1] = (bf16)a.y; v[2] = (bf16)a.z; v[3] = (bf16)a.w;
    v[4] = (bf16)b.x; v[5] = (bf16)b.y; v[6] = (bf16)b.z; v[7] = (bf16)b.w;
    *(bf16x8*)&dst[i] = v;
}

// ---------------------------------------------------------------------------
// bf16 GEMM, C = A @ W^T. 64x64 tile, 4 waves each 32x32. BK=128 as four
// proven glds half-tiles (8 barrier pairs for K=1024, 16 MFMA per pair per
// wave). LDS 32 KB -> 5 blocks/CU.
// mode 0: Q (rope+QSCALE) / K (rope) / V (transposed store into Vt) split.
// mode 1: single fp32 output Co.
// ---------------------------------------------------------------------------
__global__ __launch_bounds__(256, 5)
void gemm_t64(const bf16* __restrict__ A, const bf16* __restrict__ W, int K,
              bf16* __restrict__ Cq, bf16* __restrict__ Ck, bf16* __restrict__ Vt,
              float* __restrict__ Co, const int* __restrict__ pos, int mode)
{
    __shared__ bf16 As[4][64 * 32];   // 16 KB
    __shared__ bf16 Bs[4][64 * 32];   // 16 KB

    const int tid  = threadIdx.x;
    const int wave = tid >> 6;
    const int lane = tid & 63;
    const int lr   = lane & 15;
    const int quad = lane >> 4;
    const int m0 = blockIdx.y * 64;
    const int n0 = blockIdx.x * 64;
    const int wm = (wave >> 1) * 32;
    const int wn = (wave & 1) * 32;

    // staging: wave w deposits rows w*16..w*16+15 of each 64x32 half-tile;
    // lane L -> row L>>2, col (L&3)*8 (proven lane-order glds layout)
    const int srow = (lane >> 2);
    const int scol = (lane & 3) * 8;
    const bf16* Ap = &A[(size_t)(m0 + wave * 16 + srow) * K + scol];
    const bf16* Wp = &W[(size_t)(n0 + wave * 16 + srow) * K + scol];

    floatx4 acc[2][2];
#pragma unroll
    for (int i = 0; i < 2; i++)
#pragma unroll
        for (int j = 0; j < 2; j++) acc[i][j] = (floatx4)(0.0f);

    for (int k0 = 0; k0 < K; k0 += 128) {
        __syncthreads();
#pragma unroll
        for (int hh = 0; hh < 4; hh++) {
            GLDS16(Ap + k0 + hh * 32, &As[hh][wave * 512]);
            GLDS16(Wp + k0 + hh * 32, &Bs[hh][wave * 512]);
        }
        __syncthreads();

        bf16x8 a[2][4], b[2][4];
#pragma unroll
        for (int mi = 0; mi < 2; mi++)
#pragma unroll
            for (int hh = 0; hh < 4; hh++)
                a[mi][hh] = *(const bf16x8*)&As[hh][(wm + mi * 16 + lr) * 32 + quad * 8];
#pragma unroll
        for (int ni = 0; ni < 2; ni++)
#pragma unroll
            for (int hh = 0; hh < 4; hh++)
                b[ni][hh] = *(const bf16x8*)&Bs[hh][(wn + ni * 16 + lr) * 32 + quad * 8];

#pragma unroll
        for (int mi = 0; mi < 2; mi++)
#pragma unroll
            for (int ni = 0; ni < 2; ni++)
#pragma unroll
                for (int hh = 0; hh < 4; hh++)
                    acc[mi][ni] = __builtin_amdgcn_mfma_f32_16x16x32_bf16(
                        a[mi][hh], b[ni][hh], acc[mi][ni], 0, 0, 0);
    }

    if (mode == 0) {
        if (n0 >= D_MODEL + KV_DIM) {
            // ---- V: store transposed into Vt[(bg*64+d)*SEQ_T + t] ----
            const int g  = (n0 - (D_MODEL + KV_DIM)) >> 6;   // 0..3
            const int b  = m0 >> 11;
            const int bg = b * 4 + g;
#pragma unroll
            for (int mi = 0; mi < 2; mi++) {
#pragma unroll
                for (int ni = 0; ni < 2; ni++) {
                    int d  = wn + ni * 16 + lr;
                    int t0 = (m0 & (SEQ_T - 1)) + wm + mi * 16 + quad * 4;
                    bf16x4 v;
#pragma unroll
                    for (int r = 0; r < 4; r++) v[r] = (bf16)acc[mi][ni][r];
                    *(bf16x4*)&Vt[((size_t)(bg * 64 + d)) * SEQ_T + t0] = v;
                }
            }
        } else {
            // ---- Q / K: RoPE epilogue ----
            bf16* out; int ld, coff; float sc;
            if (n0 < D_MODEL) { out = Cq; ld = D_MODEL; coff = n0; sc = QSCALE; }
            else              { out = Ck; ld = KV_DIM;  coff = n0 - D_MODEL; sc = 1.0f; }
            float inv[2];
            float sgn = (lr & 1) ? 1.0f : -1.0f;
#pragma unroll
            for (int ni = 0; ni < 2; ni++) {
                int ip = (wn + ni * 16 + lr) >> 1;      // pair index 0..31 within head
                inv[ni] = exp2f(-(float)ip * FREQ_C);
            }
#pragma unroll
            for (int mi = 0; mi < 2; mi++) {
#pragma unroll
                for (int r = 0; r < 4; r++) {
                    int row = m0 + wm + mi * 16 + quad * 4 + r;
                    float p = (float)pos[row & (SEQ_T - 1)];
#pragma unroll
                    for (int ni = 0; ni < 2; ni++) {
                        float v  = acc[mi][ni][r];
                        float vp = __shfl_xor(v, 1);
                        float ang = p * inv[ni];
                        float ss, cc;
                        __sincosf(ang, &ss, &cc);
                        v = v * cc + vp * ss * sgn;     // even: x1 c - x2 s ; odd: x1 s + x2 c
                        out[(size_t)row * ld + coff + wn + ni * 16 + lr] = (bf16)(v * sc);
                    }
                }
            }
        }
    } else {
#pragma unroll
        for (int mi = 0; mi < 2; mi++)
#pragma unroll
            for (int ni = 0; ni < 2; ni++)
#pragma unroll
                for (int r = 0; r < 4; r++) {
                    int row = m0 + wm + mi * 16 + quad * 4 + r;
                    int col = n0 + wn + ni * 16 + lr;
                    Co[(size_t)row * D_MODEL + col] = acc[mi][ni][r];
                }
    }
}

// ---------------------------------------------------------------------------
// GQA-fused MFMA flash attention with manual K/V prefetch: tile j+1's global
// loads are issued right after tile j's staging barrier, overlapping L2
// latency with the MFMA/exp2 section. Block = (b, group, 32-query tile);
// wave w = head 4g+w; K/Vt staged once per block (shared by 4 heads).
// ---------------------------------------------------------------------------
__global__ __launch_bounds__(256)
void attn_mfma(const bf16* __restrict__ Q, const bf16* __restrict__ K,
               const bf16* __restrict__ Vt_g, bf16* __restrict__ AO)
{
    const int ST = 72;
    __shared__ bf16 Ks[64 * ST];
    __shared__ bf16 Vt[80 * ST];        // row 64 = ones
    __shared__ bf16 Ps[4 * 32 * ST];    // wave-private P

    const int tid  = threadIdx.x;
    const int wave = tid >> 6;
    const int lane = tid & 63;
    const int lr   = lane & 15;
    const int quad = lane >> 4;
    const int bg = blockIdx.y;
    const int b = bg >> 2, g = bg & 3;
    const int h = g * 4 + wave;
    const int q0 = blockIdx.x * 32;

    bf16x8 qf[2][2];
#pragma unroll
    for (int mi = 0; mi < 2; mi++)
#pragma unroll
        for (int ks = 0; ks < 2; ks++)
            qf[mi][ks] = *(const bf16x8*)
                &Q[((size_t)(b * SEQ_T + q0 + mi * 16 + lr)) * D_MODEL
                   + h * 64 + ks * 32 + quad * 8];

    for (int i = tid; i < 15 * ST; i += 256) Vt[65 * ST + i] = (bf16)0.0f;
    if (tid < ST) Vt[64 * ST + tid] = (bf16)(tid < 64 ? 1.0f : 0.0f);

    bf16* Pw = &Ps[wave * 32 * ST];

    floatx4 o[2][5];
#pragma unroll
    for (int mi = 0; mi < 2; mi++)
#pragma unroll
        for (int nt = 0; nt < 5; nt++) o[mi][nt] = (floatx4)(0.0f);

    const int t0   = (q0 >= WINDOW) ? ((q0 - WINDOW) & ~63) : 0;
    const int last = q0 & ~63;

    // staging address components (2 chunks/thread)
    const int srw0 = tid >> 3,        scl0 = (tid & 7) * 8;
    const int srw1 = (tid + 256) >> 3, scl1 = ((tid + 256) & 7) * 8;

    // prefetch first tile into registers
    bf16x8 kr0, kr1, vr0, vr1;
    kr0 = *(const bf16x8*)&K[((size_t)(b * SEQ_T + t0 + srw0)) * KV_DIM + g * 64 + scl0];
    kr1 = *(const bf16x8*)&K[((size_t)(b * SEQ_T + t0 + srw1)) * KV_DIM + g * 64 + scl1];
    vr0 = *(const bf16x8*)&Vt_g[((size_t)(bg * 64 + srw0)) * SEQ_T + t0 + scl0];
    vr1 = *(const bf16x8*)&Vt_g[((size_t)(bg * 64 + srw1)) * SEQ_T + t0 + scl1];

    for (int j0 = t0; j0 <= last; j0 += 64) {
        const bool mC = (j0 == last);
        const bool mW = (q0 >= WINDOW) && (j0 == t0);
        __syncthreads();   // prev-iter readers done (also covers ones-row init)
        *(bf16x8*)&Ks[srw0 * ST + scl0] = kr0;
        *(bf16x8*)&Ks[srw1 * ST + scl1] = kr1;
        *(bf16x8*)&Vt[srw0 * ST + scl0] = vr0;
        *(bf16x8*)&Vt[srw1 * ST + scl1] = vr1;
        __syncthreads();

        // issue next tile's loads (overlap with compute below)
        if (j0 + 64 <= last) {
            int jn = j0 + 64;
            kr0 = *(const bf16x8*)&K[((size_t)(b * SEQ_T + jn + srw0)) * KV_DIM + g * 64 + scl0];
            kr1 = *(const bf16x8*)&K[((size_t)(b * SEQ_T + jn + srw1)) * KV_DIM + g * 64 + scl1];
            vr0 = *(const bf16x8*)&Vt_g[((size_t)(bg * 64 + srw0)) * SEQ_T + jn + scl0];
            vr1 = *(const bf16x8*)&Vt_g[((size_t)(bg * 64 + srw1)) * SEQ_T + jn + scl1];
        }

        floatx4 s[2][4];
#pragma unroll
        for (int mi = 0; mi < 2; mi++)
#pragma unroll
            for (int nt = 0; nt < 4; nt++) s[mi][nt] = (floatx4)(0.0f);
#pragma unroll
        for (int ks = 0; ks < 2; ks++) {
#pragma unroll
            for (int nt = 0; nt < 4; nt++) {
                bf16x8 kf = *(const bf16x8*)&Ks[(nt * 16 + lr) * ST + ks * 32 + quad * 8];
                s[0][nt] = __builtin_amdgcn_mfma_f32_16x16x32_bf16(qf[0][ks], kf, s[0][nt], 0, 0, 0);
                s[1][nt] = __builtin_amdgcn_mfma_f32_16x16x32_bf16(qf[1][ks], kf, s[1][nt], 0, 0, 0);
            }
        }

        if (mC) {
#pragma unroll
            for (int mi = 0; mi < 2; mi++)
#pragma unroll
                for (int nt = 0; nt < 4; nt++) {
                    int key = j0 + nt * 16 + lr;
#pragma unroll
                    for (int r = 0; r < 4; r++) {
                        int qi_ = q0 + mi * 16 + quad * 4 + r;
                        s[mi][nt][r] = (key <= qi_) ? s[mi][nt][r] : -1e30f;
                    }
                }
        } else if (mW) {
#pragma unroll
            for (int mi = 0; mi < 2; mi++)
#pragma unroll
                for (int nt = 0; nt < 4; nt++) {
                    int key = j0 + nt * 16 + lr;
#pragma unroll
                    for (int r = 0; r < 4; r++) {
                        int qi_ = q0 + mi * 16 + quad * 4 + r;
                        s[mi][nt][r] = (qi_ - key <= WINDOW) ? s[mi][nt][r] : -1e30f;
                    }
                }
        }

#pragma unroll
        for (int mi = 0; mi < 2; mi++)
#pragma unroll
            for (int nt = 0; nt < 4; nt++)
#pragma unroll
                for (int r = 0; r < 4; r++)
                    Pw[(mi * 16 + quad * 4 + r) * ST + nt * 16 + lr] =
                        (bf16)exp2f(s[mi][nt][r]);

        __asm__ volatile("s_waitcnt lgkmcnt(0)" ::: "memory");

#pragma unroll
        for (int ks = 0; ks < 2; ks++) {
            bf16x8 pf0 = *(const bf16x8*)&Pw[(0 + lr) * ST + ks * 32 + quad * 8];
            bf16x8 pf1 = *(const bf16x8*)&Pw[(16 + lr) * ST + ks * 32 + quad * 8];
#pragma unroll
            for (int nt = 0; nt < 5; nt++) {
                bf16x8 vf = *(const bf16x8*)&Vt[(nt * 16 + lr) * ST + ks * 32 + quad * 8];
                o[0][nt] = __builtin_amdgcn_mfma_f32_16x16x32_bf16(pf0, vf, o[0][nt], 0, 0, 0);
                o[1][nt] = __builtin_amdgcn_mfma_f32_16x16x32_bf16(pf1, vf, o[1][nt], 0, 0, 0);
            }
        }
    }

#pragma unroll
    for (int mi = 0; mi < 2; mi++)
#pragma unroll
        for (int r = 0; r < 4; r++) {
            float l = __shfl(o[mi][4][r], lane & 48);
            float invl = 1.0f / l;
            int row = q0 + mi * 16 + quad * 4 + r;
#pragma unroll
            for (int nt = 0; nt < 4; nt++)
                AO[((size_t)(b * SEQ_T + row)) * D_MODEL + h * 64 + nt * 16 + lr] =
                    (bf16)(o[mi][nt][r] * invl);
        }
}

// ---------------------------------------------------------------------------
extern "C" void kernel_launch(void* const* d_in, const int* in_sizes, int n_in,
                              void* d_out, int out_size, void* d_ws, size_t ws_size,
                              hipStream_t stream)
{
    const float* x  = (const float*)d_in[0];
    const float* WQ = (const float*)d_in[1];
    const float* WK = (const float*)d_in[2];
    const float* WV = (const float*)d_in[3];
    const float* WO = (const float*)d_in[4];
    const int*  pos = (const int*)d_in[5];

    // ws: Qw 8MB | Kw 2MB | Vt_g 2MB | xb/AO 8MB | Wqkv 3MB | WOb 2MB
    char* ws   = (char*)d_ws;
    bf16* Qw   = (bf16*)ws;
    bf16* Kw   = (bf16*)(ws + (size_t) 8 * 1024 * 1024);
    bf16* Vt_g = (bf16*)(ws + (size_t)10 * 1024 * 1024);
    bf16* xb   = (bf16*)(ws + (size_t)12 * 1024 * 1024);
    bf16* AO   = xb;                                        // overlay (xb dead)
    bf16* Wqkv = (bf16*)(ws + (size_t)20 * 1024 * 1024);
    bf16* WOb  = (bf16*)(ws + (size_t)23 * 1024 * 1024);

    const int cx = (M_ROWS * D_MODEL) / 8;
    const int cq = (D_MODEL * D_MODEL) / 8;
    const int ck = (KV_DIM * D_MODEL) / 8;
    const int ctot = cx + cq + 2 * ck + cq;
    convert_all<<<ctot / 256, 256, 0, stream>>>(
        x, xb, cx,
        WQ, Wqkv, cq,
        WK, Wqkv + (size_t)D_MODEL * D_MODEL, ck,
        WV, Wqkv + (size_t)(D_MODEL + KV_DIM) * D_MODEL, ck,
        WO, WOb, cq);

    // fused QKV projection + RoPE epilogue + V-transpose epilogue
    gemm_t64<<<dim3(N_QKV / 64, M_ROWS / 64), 256, 0, stream>>>(
        xb, Wqkv, D_MODEL, Qw, Kw, Vt_g, nullptr, pos, 0);

    // GQA-fused attention
    attn_mfma<<<dim3(SEQ_T / 32, BATCH * NUM_GROUPS), 256, 0, stream>>>(
        Qw, Kw, Vt_g, AO);

    // output projection -> fp32 d_out
    gemm_t64<<<dim3(D_MODEL / 64, M_ROWS / 64), 256, 0, stream>>>(
        AO, WOb, D_MODEL, nullptr, nullptr, nullptr, (float*)d_out, pos, 1);
}

// Round 12
// 150.068 us; speedup vs baseline: 1.0086x; 1.0086x over previous
//
#include <hip/hip_runtime.h>
#include <hip/hip_bf16.h>

typedef __bf16 bf16;
typedef __bf16 bf16x4 __attribute__((ext_vector_type(4)));
typedef __bf16 bf16x8 __attribute__((ext_vector_type(8)));
typedef float  floatx4 __attribute__((ext_vector_type(4)));

#define D_MODEL   1024
#define NUM_HEADS 16
#define NUM_GROUPS 4
#define DK        64
#define SEQ_T     2048
#define BATCH     2
#define M_ROWS    (BATCH*SEQ_T)   // 4096
#define WINDOW    512
#define KV_DIM    (NUM_GROUPS*DK) // 256
#define N_QKV     (D_MODEL + 2*KV_DIM)  // 1536
// Q pre-scale: 1/sqrt(64) * log2(e)  (exp -> exp2 domain)
#define QSCALE    0.1803368801111204f
// log2(10000)/32
#define FREQ_C    0.4152410118609203f

#define GLDS16(g, l)                                                          \
    __builtin_amdgcn_global_load_lds(                                         \
        (const __attribute__((address_space(1))) void*)(g),                   \
        (__attribute__((address_space(3))) void*)(l), 16, 0, 0)

// ---------------------------------------------------------------------------
// Fused convert: 5 fp32 segments (x, WQ, WK, WV, WO) -> bf16 dsts.
// ---------------------------------------------------------------------------
__global__ __launch_bounds__(256)
void convert_all(const float* s0, bf16* d0, int c0,
                 const float* s1, bf16* d1, int c1,
                 const float* s2, bf16* d2, int c2,
                 const float* s3, bf16* d3, int c3,
                 const float* s4, bf16* d4, int c4)
{
    int id = blockIdx.x * 256 + threadIdx.x;
    const float* src; bf16* dst;
    if      (id < c0)         { src = s0; dst = d0; }
    else if ((id -= c0) < c1) { src = s1; dst = d1; }
    else if ((id -= c1) < c2) { src = s2; dst = d2; }
    else if ((id -= c2) < c3) { src = s3; dst = d3; }
    else if ((id -= c3) < c4) { src = s4; dst = d4; }
    else return;
    int i = id * 8;
    const float* s = src + i;
    float4 a = *(const float4*)s;
    float4 b = *(const float4*)(s + 4);
    bf16x8 v;
    v[0] = (bf16)a.x; v[1] = (bf16)a.y; v[2] = (bf16)a.z; v[3] = (bf16)a.w;
    v[4] = (bf16)b.x; v[5] = (bf16)b.y; v[6] = (bf16)b.z; v[7] = (bf16)b.w;
    *(bf16x8*)&dst[i] = v;
}

// ---------------------------------------------------------------------------
// bf16 GEMM, C = A @ W^T. 64x64 tile (QKV grid 1536 = 6 blk/CU, O-proj 1024
// = 4 blk/CU). 4 waves, each 32x32 (2x2 acc), BK=64 as two proven glds
// half-tiles; 8 MFMA / iter / wave.
// mode 0: Q (rope+QSCALE) / K (rope) / V (transposed store into Vt) split.
// mode 1: single fp32 output Co.
// ---------------------------------------------------------------------------
__global__ __launch_bounds__(256, 6)
void gemm_t64(const bf16* __restrict__ A, const bf16* __restrict__ W, int K,
              bf16* __restrict__ Cq, bf16* __restrict__ Ck, bf16* __restrict__ Vt,
              float* __restrict__ Co, const int* __restrict__ pos, int mode)
{
    __shared__ bf16 As0[64 * 32], As1[64 * 32];   // 4 KB each
    __shared__ bf16 Bs0[64 * 32], Bs1[64 * 32];   // 4 KB each

    const int tid  = threadIdx.x;
    const int wave = tid >> 6;
    const int lane = tid & 63;
    const int lr   = lane & 15;
    const int quad = lane >> 4;
    const int m0 = blockIdx.y * 64;
    const int n0 = blockIdx.x * 64;
    const int wm = (wave >> 1) * 32;
    const int wn = (wave & 1) * 32;

    // staging: wave w deposits rows w*16..w*16+15 of each 64x32 half-tile;
    // lane L -> row L>>2, col (L&3)*8 (proven lane-order glds layout)
    const int srow = (lane >> 2);
    const int scol = (lane & 3) * 8;
    const bf16* Ap = &A[(size_t)(m0 + wave * 16 + srow) * K + scol];
    const bf16* Wp = &W[(size_t)(n0 + wave * 16 + srow) * K + scol];
    bf16* As0d = &As0[wave * 512];
    bf16* As1d = &As1[wave * 512];
    bf16* Bs0d = &Bs0[wave * 512];
    bf16* Bs1d = &Bs1[wave * 512];

    floatx4 acc[2][2];
#pragma unroll
    for (int i = 0; i < 2; i++)
#pragma unroll
        for (int j = 0; j < 2; j++) acc[i][j] = (floatx4)(0.0f);

    for (int k0 = 0; k0 < K; k0 += 64) {
        __syncthreads();
        GLDS16(Ap + k0,      As0d);
        GLDS16(Ap + k0 + 32, As1d);
        GLDS16(Wp + k0,      Bs0d);
        GLDS16(Wp + k0 + 32, Bs1d);
        __syncthreads();

        bf16x8 a0[2], a1[2], b0[2], b1[2];
#pragma unroll
        for (int mi = 0; mi < 2; mi++) {
            a0[mi] = *(const bf16x8*)&As0[(wm + mi * 16 + lr) * 32 + quad * 8];
            a1[mi] = *(const bf16x8*)&As1[(wm + mi * 16 + lr) * 32 + quad * 8];
        }
#pragma unroll
        for (int ni = 0; ni < 2; ni++) {
            b0[ni] = *(const bf16x8*)&Bs0[(wn + ni * 16 + lr) * 32 + quad * 8];
            b1[ni] = *(const bf16x8*)&Bs1[(wn + ni * 16 + lr) * 32 + quad * 8];
        }

#pragma unroll
        for (int mi = 0; mi < 2; mi++)
#pragma unroll
            for (int ni = 0; ni < 2; ni++) {
                acc[mi][ni] = __builtin_amdgcn_mfma_f32_16x16x32_bf16(
                    a0[mi], b0[ni], acc[mi][ni], 0, 0, 0);
                acc[mi][ni] = __builtin_amdgcn_mfma_f32_16x16x32_bf16(
                    a1[mi], b1[ni], acc[mi][ni], 0, 0, 0);
            }
    }

    if (mode == 0) {
        if (n0 >= D_MODEL + KV_DIM) {
            // ---- V: store transposed into Vt[(bg*64+d)*SEQ_T + t] ----
            const int g  = (n0 - (D_MODEL + KV_DIM)) >> 6;   // 0..3
            const int b  = m0 >> 11;
            const int bg = b * 4 + g;
#pragma unroll
            for (int mi = 0; mi < 2; mi++) {
#pragma unroll
                for (int ni = 0; ni < 2; ni++) {
                    int d  = wn + ni * 16 + lr;
                    int t0 = (m0 & (SEQ_T - 1)) + wm + mi * 16 + quad * 4;
                    bf16x4 v;
#pragma unroll
                    for (int r = 0; r < 4; r++) v[r] = (bf16)acc[mi][ni][r];
                    *(bf16x4*)&Vt[((size_t)(bg * 64 + d)) * SEQ_T + t0] = v;
                }
            }
        } else {
            // ---- Q / K: RoPE epilogue ----
            bf16* out; int ld, coff; float sc;
            if (n0 < D_MODEL) { out = Cq; ld = D_MODEL; coff = n0; sc = QSCALE; }
            else              { out = Ck; ld = KV_DIM;  coff = n0 - D_MODEL; sc = 1.0f; }
            float inv[2];
            float sgn = (lr & 1) ? 1.0f : -1.0f;
#pragma unroll
            for (int ni = 0; ni < 2; ni++) {
                int ip = (wn + ni * 16 + lr) >> 1;      // pair index 0..31 within head
                inv[ni] = exp2f(-(float)ip * FREQ_C);
            }
#pragma unroll
            for (int mi = 0; mi < 2; mi++) {
#pragma unroll
                for (int r = 0; r < 4; r++) {
                    int row = m0 + wm + mi * 16 + quad * 4 + r;
                    float p = (float)pos[row & (SEQ_T - 1)];
#pragma unroll
                    for (int ni = 0; ni < 2; ni++) {
                        float v  = acc[mi][ni][r];
                        float vp = __shfl_xor(v, 1);
                        float ang = p * inv[ni];
                        float ss, cc;
                        __sincosf(ang, &ss, &cc);
                        v = v * cc + vp * ss * sgn;     // even: x1 c - x2 s ; odd: x1 s + x2 c
                        out[(size_t)row * ld + coff + wn + ni * 16 + lr] = (bf16)(v * sc);
                    }
                }
            }
        }
    } else {
#pragma unroll
        for (int mi = 0; mi < 2; mi++)
#pragma unroll
            for (int ni = 0; ni < 2; ni++)
#pragma unroll
                for (int r = 0; r < 4; r++) {
                    int row = m0 + wm + mi * 16 + quad * 4 + r;
                    int col = n0 + wn + ni * 16 + lr;
                    Co[(size_t)row * D_MODEL + col] = acc[mi][ni][r];
                }
    }
}

// ---------------------------------------------------------------------------
// GQA-fused MFMA flash attention. Block = (b, group, 32-query tile); wave w
// = head 4g+w; K/Vt staged once per block (shared by 4 heads). No-max
// softmax (Q pre-scaled to exp2 domain, scores bounded); l via MFMA
// ones-column; P wave-private. LDS 39.2 KB.
// ---------------------------------------------------------------------------
__global__ __launch_bounds__(256)
void attn_mfma(const bf16* __restrict__ Q, const bf16* __restrict__ K,
               const bf16* __restrict__ Vt_g, bf16* __restrict__ AO)
{
    const int ST = 72;
    __shared__ bf16 Ks[64 * ST];
    __shared__ bf16 Vt[80 * ST];        // row 64 = ones
    __shared__ bf16 Ps[4 * 32 * ST];    // wave-private P

    const int tid  = threadIdx.x;
    const int wave = tid >> 6;
    const int lane = tid & 63;
    const int lr   = lane & 15;
    const int quad = lane >> 4;
    const int bg = blockIdx.y;
    const int b = bg >> 2, g = bg & 3;
    const int h = g * 4 + wave;
    const int q0 = blockIdx.x * 32;

    bf16x8 qf[2][2];
#pragma unroll
    for (int mi = 0; mi < 2; mi++)
#pragma unroll
        for (int ks = 0; ks < 2; ks++)
            qf[mi][ks] = *(const bf16x8*)
                &Q[((size_t)(b * SEQ_T + q0 + mi * 16 + lr)) * D_MODEL
                   + h * 64 + ks * 32 + quad * 8];

    for (int i = tid; i < 15 * ST; i += 256) Vt[65 * ST + i] = (bf16)0.0f;
    if (tid < ST) Vt[64 * ST + tid] = (bf16)(tid < 64 ? 1.0f : 0.0f);

    bf16* Pw = &Ps[wave * 32 * ST];

    floatx4 o[2][5];
#pragma unroll
    for (int mi = 0; mi < 2; mi++)
#pragma unroll
        for (int nt = 0; nt < 5; nt++) o[mi][nt] = (floatx4)(0.0f);

    const int t0   = (q0 >= WINDOW) ? ((q0 - WINDOW) & ~63) : 0;
    const int last = q0 & ~63;

    for (int j0 = t0; j0 <= last; j0 += 64) {
        const bool mC = (j0 == last);
        const bool mW = (q0 >= WINDOW) && (j0 == t0);
        __syncthreads();
#pragma unroll
        for (int i = 0; i < 2; i++) {
            int c = tid + i * 256;
            int row = c >> 3, col8 = (c & 7) * 8;
            *(bf16x8*)&Ks[row * ST + col8] =
                *(const bf16x8*)&K[((size_t)(b * SEQ_T + j0 + row)) * KV_DIM + g * 64 + col8];
            *(bf16x8*)&Vt[row * ST + col8] =
                *(const bf16x8*)&Vt_g[((size_t)(bg * 64 + row)) * SEQ_T + j0 + col8];
        }
        __syncthreads();

        floatx4 s[2][4];
#pragma unroll
        for (int mi = 0; mi < 2; mi++)
#pragma unroll
            for (int nt = 0; nt < 4; nt++) s[mi][nt] = (floatx4)(0.0f);
#pragma unroll
        for (int ks = 0; ks < 2; ks++) {
#pragma unroll
            for (int nt = 0; nt < 4; nt++) {
                bf16x8 kf = *(const bf16x8*)&Ks[(nt * 16 + lr) * ST + ks * 32 + quad * 8];
                s[0][nt] = __builtin_amdgcn_mfma_f32_16x16x32_bf16(qf[0][ks], kf, s[0][nt], 0, 0, 0);
                s[1][nt] = __builtin_amdgcn_mfma_f32_16x16x32_bf16(qf[1][ks], kf, s[1][nt], 0, 0, 0);
            }
        }

        if (mC) {
#pragma unroll
            for (int mi = 0; mi < 2; mi++)
#pragma unroll
                for (int nt = 0; nt < 4; nt++) {
                    int key = j0 + nt * 16 + lr;
#pragma unroll
                    for (int r = 0; r < 4; r++) {
                        int qi_ = q0 + mi * 16 + quad * 4 + r;
                        s[mi][nt][r] = (key <= qi_) ? s[mi][nt][r] : -1e30f;
                    }
                }
        } else if (mW) {
#pragma unroll
            for (int mi = 0; mi < 2; mi++)
#pragma unroll
                for (int nt = 0; nt < 4; nt++) {
                    int key = j0 + nt * 16 + lr;
#pragma unroll
                    for (int r = 0; r < 4; r++) {
                        int qi_ = q0 + mi * 16 + quad * 4 + r;
                        s[mi][nt][r] = (qi_ - key <= WINDOW) ? s[mi][nt][r] : -1e30f;
                    }
                }
        }

#pragma unroll
        for (int mi = 0; mi < 2; mi++)
#pragma unroll
            for (int nt = 0; nt < 4; nt++)
#pragma unroll
                for (int r = 0; r < 4; r++)
                    Pw[(mi * 16 + quad * 4 + r) * ST + nt * 16 + lr] =
                        (bf16)exp2f(s[mi][nt][r]);

        __asm__ volatile("s_waitcnt lgkmcnt(0)" ::: "memory");

#pragma unroll
        for (int ks = 0; ks < 2; ks++) {
            bf16x8 pf0 = *(const bf16x8*)&Pw[(0 + lr) * ST + ks * 32 + quad * 8];
            bf16x8 pf1 = *(const bf16x8*)&Pw[(16 + lr) * ST + ks * 32 + quad * 8];
#pragma unroll
            for (int nt = 0; nt < 5; nt++) {
                bf16x8 vf = *(const bf16x8*)&Vt[(nt * 16 + lr) * ST + ks * 32 + quad * 8];
                o[0][nt] = __builtin_amdgcn_mfma_f32_16x16x32_bf16(pf0, vf, o[0][nt], 0, 0, 0);
                o[1][nt] = __builtin_amdgcn_mfma_f32_16x16x32_bf16(pf1, vf, o[1][nt], 0, 0, 0);
            }
        }
    }

#pragma unroll
    for (int mi = 0; mi < 2; mi++)
#pragma unroll
        for (int r = 0; r < 4; r++) {
            float l = __shfl(o[mi][4][r], lane & 48);
            float invl = 1.0f / l;
            int row = q0 + mi * 16 + quad * 4 + r;
#pragma unroll
            for (int nt = 0; nt < 4; nt++)
                AO[((size_t)(b * SEQ_T + row)) * D_MODEL + h * 64 + nt * 16 + lr] =
                    (bf16)(o[mi][nt][r] * invl);
        }
}

// ---------------------------------------------------------------------------
extern "C" void kernel_launch(void* const* d_in, const int* in_sizes, int n_in,
                              void* d_out, int out_size, void* d_ws, size_t ws_size,
                              hipStream_t stream)
{
    const float* x  = (const float*)d_in[0];
    const float* WQ = (const float*)d_in[1];
    const float* WK = (const float*)d_in[2];
    const float* WV = (const float*)d_in[3];
    const float* WO = (const float*)d_in[4];
    const int*  pos = (const int*)d_in[5];

    // ws: Qw 8MB | Kw 2MB | Vt_g 2MB | xb/AO 8MB | Wqkv 3MB | WOb 2MB
    char* ws   = (char*)d_ws;
    bf16* Qw   = (bf16*)ws;
    bf16* Kw   = (bf16*)(ws + (size_t) 8 * 1024 * 1024);
    bf16* Vt_g = (bf16*)(ws + (size_t)10 * 1024 * 1024);
    bf16* xb   = (bf16*)(ws + (size_t)12 * 1024 * 1024);
    bf16* AO   = xb;                                        // overlay (xb dead)
    bf16* Wqkv = (bf16*)(ws + (size_t)20 * 1024 * 1024);
    bf16* WOb  = (bf16*)(ws + (size_t)23 * 1024 * 1024);

    const int cx = (M_ROWS * D_MODEL) / 8;
    const int cq = (D_MODEL * D_MODEL) / 8;
    const int ck = (KV_DIM * D_MODEL) / 8;
    const int ctot = cx + cq + 2 * ck + cq;
    convert_all<<<ctot / 256, 256, 0, stream>>>(
        x, xb, cx,
        WQ, Wqkv, cq,
        WK, Wqkv + (size_t)D_MODEL * D_MODEL, ck,
        WV, Wqkv + (size_t)(D_MODEL + KV_DIM) * D_MODEL, ck,
        WO, WOb, cq);

    // fused QKV projection + RoPE epilogue + V-transpose epilogue
    gemm_t64<<<dim3(N_QKV / 64, M_ROWS / 64), 256, 0, stream>>>(
        x ? xb : xb, Wqkv, D_MODEL, Qw, Kw, Vt_g, nullptr, pos, 0);

    // GQA-fused attention
    attn_mfma<<<dim3(SEQ_T / 32, BATCH * NUM_GROUPS), 256, 0, stream>>>(
        Qw, Kw, Vt_g, AO);

    // output projection -> fp32 d_out
    gemm_t64<<<dim3(D_MODEL / 64, M_ROWS / 64), 256, 0, stream>>>(
        AO, WOb, D_MODEL, nullptr, nullptr, nullptr, (float*)d_out, pos, 1);
}